// Round 14
// baseline (361.500 us; speedup 1.0000x reference)
//
#include <hip/hip_runtime.h>
#include <hip/hip_bf16.h>

typedef __attribute__((ext_vector_type(8))) short short8;       // 8 bf16 (A/B frag)
typedef __attribute__((ext_vector_type(4))) float floatx4;      // C/D frag
typedef __attribute__((ext_vector_type(4))) unsigned short ushort4v;
typedef _Float16 half2v __attribute__((ext_vector_type(2)));
typedef __fp16 fp16v2 __attribute__((ext_vector_type(2)));

__device__ inline unsigned short f2bf(float x) {                 // RNE f32->bf16 bits
    unsigned int u = __float_as_uint(x);
    u += 0x7FFFu + ((u >> 16) & 1u);
    return (unsigned short)(u >> 16);
}
__device__ inline float bf2f(unsigned short h) {
    return __uint_as_float(((unsigned int)h) << 16);
}
__device__ inline unsigned int pkh(float a, float b) {           // 2xf32 -> packed f16
    fp16v2 h = __builtin_amdgcn_cvt_pkrtz(a, b);
    unsigned int u; __builtin_memcpy(&u, &h, 4); return u;
}
__device__ inline half2v uh(unsigned int u) {
    half2v h; __builtin_memcpy(&h, &u, 4); return h;
}

// ---------------- CSR build ----------------
__global__ __launch_bounds__(256) void hist_kernel(
    const int* __restrict__ dst, int* __restrict__ deg, int E)
{
    int e = blockIdx.x * blockDim.x + threadIdx.x;
    if (e < E) atomicAdd(&deg[dst[e]], 1);
}

// hierarchical scan: block sums -> top scan (<=64 blocks) -> add-back
__global__ __launch_bounds__(256) void scan_part(
    const int* __restrict__ deg, int* __restrict__ bsum, int N)
{
    __shared__ int ws[4];
    const int base = blockIdx.x * 1024;
    const int tid = threadIdx.x, lane = tid & 63, w = tid >> 6;
    int s = 0;
#pragma unroll
    for (int j = 0; j < 4; j++) {
        int i = base + j * 256 + tid;
        if (i < N) s += deg[i];
    }
#pragma unroll
    for (int off = 1; off < 64; off <<= 1) s += __shfl_xor(s, off, 64);
    if (lane == 0) ws[w] = s;
    __syncthreads();
    if (tid == 0) bsum[blockIdx.x] = ws[0] + ws[1] + ws[2] + ws[3];
}

__global__ __launch_bounds__(64) void scan_tops(
    const int* __restrict__ bsum, int* __restrict__ boff,
    int* __restrict__ rowptr, int nb, int N)
{
    int lane = threadIdx.x;
    int v = (lane < nb) ? bsum[lane] : 0;
    int inc = v;
#pragma unroll
    for (int off = 1; off < 64; off <<= 1) {
        int t = __shfl_up(inc, off, 64);
        if (lane >= off) inc += t;
    }
    if (lane < nb) boff[lane] = inc - v;
    if (lane == 63) rowptr[N] = inc;
}

__global__ __launch_bounds__(256) void scan_final(
    const int* __restrict__ deg, const int* __restrict__ boff,
    int* __restrict__ rowptr, int* __restrict__ cursor, int N)
{
    __shared__ int woff[4];
    const int base = blockIdx.x * 1024;
    const int tid = threadIdx.x, lane = tid & 63, w = tid >> 6;
    const int i0 = base + tid * 4;
    int v0 = (i0     < N) ? deg[i0]     : 0;
    int v1 = (i0 + 1 < N) ? deg[i0 + 1] : 0;
    int v2 = (i0 + 2 < N) ? deg[i0 + 2] : 0;
    int v3 = (i0 + 3 < N) ? deg[i0 + 3] : 0;
    int ts = v0 + v1 + v2 + v3;
    int inc = ts;
#pragma unroll
    for (int off = 1; off < 64; off <<= 1) {
        int t = __shfl_up(inc, off, 64);
        if (lane >= off) inc += t;
    }
    if (lane == 63) woff[w] = inc;
    __syncthreads();
    int wpre = 0;
    if (w > 0) wpre += woff[0];
    if (w > 1) wpre += woff[1];
    if (w > 2) wpre += woff[2];
    int exc = boff[blockIdx.x] + wpre + inc - ts;
    int p0 = exc, p1 = exc + v0, p2 = p1 + v1, p3 = p2 + v2;
    if (i0     < N) { rowptr[i0]     = p0; cursor[i0]     = p0; }
    if (i0 + 1 < N) { rowptr[i0 + 1] = p1; cursor[i0 + 1] = p1; }
    if (i0 + 2 < N) { rowptr[i0 + 2] = p2; cursor[i0 + 2] = p2; }
    if (i0 + 3 < N) { rowptr[i0 + 3] = p3; cursor[i0 + 3] = p3; }
}

__global__ __launch_bounds__(256) void fill_kernel(
    const int* __restrict__ src, const int* __restrict__ dst,
    int* __restrict__ cursor, int* __restrict__ perm, int E)
{
    int e = blockIdx.x * blockDim.x + threadIdx.x;
    if (e >= E) return;
    int pos = atomicAdd(&cursor[dst[e]], 1);
    perm[pos] = src[e];
}

// ---------------- weight prep (both layers fused): Wt[col][k] hi/lo bf16 ----
__global__ __launch_bounds__(128) void wprep_all(
    const float* __restrict__ wq1, const float* __restrict__ bq1,
    const float* __restrict__ wk1, const float* __restrict__ bk1,
    const float* __restrict__ wv1, const float* __restrict__ bv1,
    const float* __restrict__ ws1, const float* __restrict__ bs1,
    const float* __restrict__ wq2, const float* __restrict__ bq2,
    const float* __restrict__ wk2, const float* __restrict__ bk2,
    const float* __restrict__ wv2, const float* __restrict__ bv2,
    const float* __restrict__ ws2, const float* __restrict__ bs2,
    unsigned short* __restrict__ wt1h, unsigned short* __restrict__ wt1l,
    float* __restrict__ bias1,
    unsigned short* __restrict__ wt2h, unsigned short* __restrict__ wt2l,
    float* __restrict__ bias2)
{
    const int layer = (blockIdx.x >= 416) ? 1 : 0;
    const int c = blockIdx.x - layer * 416;
    const int t = threadIdx.x;
    const int L = layer ? 32 : 128;
    if (t >= L) return;
    const float* w; const float* b; int cc, ncols;
    if (c < 384) {
        int m = c >> 7; cc = c & 127; ncols = 128;
        if (layer == 0) {
            w = (m == 0) ? wq1 : ((m == 1) ? wk1 : wv1);
            b = (m == 0) ? bq1 : ((m == 1) ? bk1 : bv1);
        } else {
            w = (m == 0) ? wq2 : ((m == 1) ? wk2 : wv2);
            b = (m == 0) ? bq2 : ((m == 1) ? bk2 : bv2);
        }
    } else {
        cc = c - 384; ncols = 32;
        w = layer ? ws2 : ws1; b = layer ? bs2 : bs1;
    }
    unsigned short* wh = layer ? wt2h : wt1h;
    unsigned short* wl = layer ? wt2l : wt1l;
    float* bias = layer ? bias2 : bias1;
    float val = w[t * ncols + cc];
    unsigned short h = f2bf(val);
    wh[c * L + t] = h;
    wl[c * L + t] = f2bf(val - bf2f(h));
    if (t == 0) bias[c] = b[cc];
}

// ---------------- K1: MFMA projection, A-stationary, coalesced stores -------
// q/k/v outputs packed f16 (qu: 64 uints/node; kvp: 128 uints/node
// interleaved [k01,v01,k23,v23] per 4-dim group). skip stays f32.
template <int L>
__global__ __launch_bounds__(256) void proj_mfma(
    const float* __restrict__ xin,
    const unsigned short* __restrict__ wt_hi,
    const unsigned short* __restrict__ wt_lo,
    const float* __restrict__ bias,
    unsigned int* __restrict__ qu, unsigned int* __restrict__ kvp,
    float* __restrict__ skip, int N)
{
    constexpr int LP = L + 8;          // ushort pad
    constexpr int KS = L / 32;
    constexpr int SI = (32 * (L / 4)) / 256;
    __shared__ unsigned short xh[2][32 * LP];
    __shared__ unsigned short xl[2][32 * LP];
    __shared__ float scr[4][32 * 36];
    const int tid = threadIdx.x, lane = tid & 63, w = tid >> 6;
    const int li = lane & 15, quad = lane >> 4;
    const int slot = __builtin_amdgcn_readfirstlane(blockIdx.y * 4 + w);
    const bool hasT = slot < 13;

    int t0 = 24, t1 = 25;
    if (slot < 4)       { t0 = slot * 2; t1 = t0 + 1; }
    else if (slot < 12) { t0 = 4 + slot; t1 = 12 + slot; }   // k=8+i, v=16+i

    short8 Ah[2][KS], Al[2][KS];
    float bias_r[2][4];
    if (hasT) {
#pragma unroll
        for (int ti = 0; ti < 2; ti++) {
            int tt = ti ? t1 : t0;
#pragma unroll
            for (int ks = 0; ks < KS; ks++) {
                long off = (long)(tt * 16 + li) * L + ks * 32 + quad * 8;
                Ah[ti][ks] = *(const short8*)(wt_hi + off);
                Al[ti][ks] = *(const short8*)(wt_lo + off);
            }
#pragma unroll
            for (int r = 0; r < 4; r++)
                bias_r[ti][r] = bias[tt * 16 + quad * 4 + r];
        }
    }

    const int nb0 = blockIdx.x * 256;
    float* myscr = scr[w];
    unsigned int* su = (unsigned int*)myscr;

    float4 xv[SI];
    auto issue_loads = [&](int c) {
#pragma unroll
        for (int s = 0; s < SI; s++) {
            int f = s * 256 + tid;
            int row = f / (L / 4), c4 = (f - row * (L / 4)) * 4;
            int n = nb0 + c * 32 + row;
            xv[s] = (n < N) ? *(const float4*)(xin + (long)n * L + c4)
                            : make_float4(0.f, 0.f, 0.f, 0.f);
        }
    };
    auto cvt_store = [&](int buf) {
#pragma unroll
        for (int s = 0; s < SI; s++) {
            int f = s * 256 + tid;
            int row = f / (L / 4), c4 = (f - row * (L / 4)) * 4;
            unsigned short h0 = f2bf(xv[s].x), h1 = f2bf(xv[s].y),
                           h2 = f2bf(xv[s].z), h3 = f2bf(xv[s].w);
            ushort4v hs = {h0, h1, h2, h3};
            ushort4v ls = {f2bf(xv[s].x - bf2f(h0)), f2bf(xv[s].y - bf2f(h1)),
                           f2bf(xv[s].z - bf2f(h2)), f2bf(xv[s].w - bf2f(h3))};
            *(ushort4v*)(xh[buf] + row * LP + c4) = hs;
            *(ushort4v*)(xl[buf] + row * LP + c4) = ls;
        }
    };

    issue_loads(0);
    cvt_store(0);
    __syncthreads();

    for (int c = 0; c < 8; c++) {
        if (c < 7) issue_loads(c + 1);
        const int n0c = nb0 + c * 32;
        if (hasT) {
            const int buf = c & 1;
#pragma unroll
            for (int half = 0; half < 2; half++) {
                short8 Bh[KS], Bl[KS];
#pragma unroll
                for (int ks = 0; ks < KS; ks++) {
                    int off = (half * 16 + li) * LP + ks * 32 + quad * 8;
                    Bh[ks] = *(const short8*)(xh[buf] + off);
                    Bl[ks] = *(const short8*)(xl[buf] + off);
                }
                floatx4 accv[2];
#pragma unroll
                for (int ti = 0; ti < 2; ti++) {
                    floatx4 acc = {0.f, 0.f, 0.f, 0.f};
#pragma unroll
                    for (int ks = 0; ks < KS; ks++) {
                        acc = __builtin_amdgcn_mfma_f32_16x16x32_bf16(Ah[ti][ks], Bh[ks], acc, 0, 0, 0);
                        acc = __builtin_amdgcn_mfma_f32_16x16x32_bf16(Ah[ti][ks], Bl[ks], acc, 0, 0, 0);
                        acc = __builtin_amdgcn_mfma_f32_16x16x32_bf16(Al[ti][ks], Bh[ks], acc, 0, 0, 0);
                    }
#pragma unroll
                    for (int r = 0; r < 4; r++) acc[r] += bias_r[ti][r];
                    accv[ti] = acc;
                }
                const int row = half * 16 + li;
                if (slot < 4) {
                    // q tiles: pack f16; row uints 0..15 = within-slot cols 0..31
                    su[row * 20 + quad * 2]         = pkh(accv[0][0], accv[0][1]);
                    su[row * 20 + quad * 2 + 1]     = pkh(accv[0][2], accv[0][3]);
                    su[row * 20 + 8 + quad * 2]     = pkh(accv[1][0], accv[1][1]);
                    su[row * 20 + 8 + quad * 2 + 1] = pkh(accv[1][2], accv[1][3]);
                } else if (slot == 12) {
                    *(floatx4*)(myscr + row * 36 + quad * 4)      = accv[0];
                    *(floatx4*)(myscr + row * 36 + 16 + quad * 4) = accv[1];
                } else {
                    // k/v pair: pack f16 [k01,v01,k23,v23]
                    uint4 pk = make_uint4(pkh(accv[0][0], accv[0][1]),
                                          pkh(accv[1][0], accv[1][1]),
                                          pkh(accv[0][2], accv[0][3]),
                                          pkh(accv[1][2], accv[1][3]));
                    *(uint4*)(su + row * 20 + quad * 4) = pk;
                }
            }
            if (slot < 4) {
#pragma unroll
                for (int it = 0; it < 2; it++) {
                    int idx = it * 64 + lane;       // 32 nodes x 4 parts
                    int nl = idx >> 2, part = idx & 3;
                    int node = n0c + nl;
                    if (node < N) {
                        uint4 vv = *(uint4*)(su + nl * 20 + part * 4);
                        *(uint4*)(qu + (long)node * 64 + slot * 16 + part * 4) = vv;
                    }
                }
            } else if (slot == 12) {
#pragma unroll
                for (int it = 0; it < 4; it++) {
                    int idx = it * 64 + lane;
                    int nl = idx >> 3, seg = idx & 7;
                    int node = n0c + nl;
                    if (node < N) {
                        floatx4 vv = *(floatx4*)(myscr + nl * 36 + seg * 4);
                        *(floatx4*)(skip + (long)node * 32 + seg * 4) = vv;
                    }
                }
            } else {
                const int i = slot - 4;
#pragma unroll
                for (int it = 0; it < 2; it++) {
                    int idx = it * 64 + lane;
                    int nl = idx >> 2, part = idx & 3;
                    int node = n0c + nl;
                    if (node < N) {
                        uint4 vv = *(uint4*)(su + nl * 20 + part * 4);
                        *(uint4*)(kvp + (long)node * 128 + i * 16 + part * 4) = vv;
                    }
                }
            }
        }
        __syncthreads();
        if (c < 7) cvt_store((c + 1) & 1);
        __syncthreads();
    }
}

// ---------------- K2: fused attention, f16 kv + fdot2, pipelined ------------
// Wave = 1 dst node. lane = [eh:1][head:2][g:3]; lane owns dims hh*32+4g..+3.
// kv uint4 at uint offset hh*32+g*4 = [k01,v01,k23,v23] (f16 pairs).
// dot: 2x v_dot2_f32_f16. 4 edges/half/iter; perm 2 iters ahead, kv 1 ahead.
template <bool FUSE_CLS>
__global__ __launch_bounds__(256) void attn_kernel(
    const unsigned int* __restrict__ qu, const unsigned int* __restrict__ kvp,
    const int* __restrict__ rowptr, const int* __restrict__ perm,
    const float* __restrict__ skip, float* __restrict__ h,
    const float* __restrict__ wc, const float* __restrict__ bc,
    float* __restrict__ out, int N)
{
    __shared__ float hrow[4][32];
    const int wid = (blockIdx.x * 256 + threadIdx.x) >> 6;
    const int wv = (threadIdx.x >> 6) & 3;
    const int lane = threadIdx.x & 63;
    if (wid >= N) return;
    const int d = __builtin_amdgcn_readfirstlane(wid);
    const int eh = lane >> 5;
    const int sl = lane & 31;
    const int hh = sl >> 3;
    const int g  = sl & 7;
    const int dimoff = hh * 32 + g * 4;    // uint offset of this lane's 4-dim kv group
    const uint2 qp = *(const uint2*)(qu + (long)d * 64 + hh * 16 + g * 2);
    const half2v qh0 = uh(qp.x), qh1 = uh(qp.y);
    const int beg = rowptr[d], end = rowptr[d + 1];
    const int n = end - beg;
    const int na = (n + 1) >> 1;
    const int my_off = beg + (eh ? na : 0);
    const int my_cnt = eh ? (n - na) : na;
    const float scale = 0.17677669529663687f;  // 1/sqrt(32)
    float m = -INFINITY, den = 0.f;
    float o0 = 0.f, o1 = 0.f, o2 = 0.f, o3 = 0.f;

    const int safe = beg;
    auto eidx = [&](int j) -> int {
        return (j < my_cnt) ? (my_off + j) : safe;
    };

    // pipeline prime: perm for j=0..7, kv for j=0..3
    int P0 = 0, P1 = 0, P2 = 0, P3 = 0;
    uint4 A0 = {0,0,0,0}, A1 = {0,0,0,0}, A2 = {0,0,0,0}, A3 = {0,0,0,0};
    if (n > 0) {
        P0 = perm[eidx(4)]; P1 = perm[eidx(5)]; P2 = perm[eidx(6)]; P3 = perm[eidx(7)];
        int s0 = perm[eidx(0)], s1 = perm[eidx(1)], s2 = perm[eidx(2)], s3 = perm[eidx(3)];
        A0 = *(const uint4*)(kvp + (long)s0 * 128 + dimoff);
        A1 = *(const uint4*)(kvp + (long)s1 * 128 + dimoff);
        A2 = *(const uint4*)(kvp + (long)s2 * 128 + dimoff);
        A3 = *(const uint4*)(kvp + (long)s3 * 128 + dimoff);
    }

    for (int j = 0; j < na; j += 4) {
        uint4 B0 = *(const uint4*)(kvp + (long)P0 * 128 + dimoff);
        uint4 B1 = *(const uint4*)(kvp + (long)P1 * 128 + dimoff);
        uint4 B2 = *(const uint4*)(kvp + (long)P2 * 128 + dimoff);
        uint4 B3 = *(const uint4*)(kvp + (long)P3 * 128 + dimoff);
        int NP0 = perm[eidx(j + 8)],  NP1 = perm[eidx(j + 9)];
        int NP2 = perm[eidx(j + 10)], NP3 = perm[eidx(j + 11)];

        float p0 = __builtin_amdgcn_fdot2(qh0, uh(A0.x), __builtin_amdgcn_fdot2(qh1, uh(A0.z), 0.f, false), false);
        float p1 = __builtin_amdgcn_fdot2(qh0, uh(A1.x), __builtin_amdgcn_fdot2(qh1, uh(A1.z), 0.f, false), false);
        float p2 = __builtin_amdgcn_fdot2(qh0, uh(A2.x), __builtin_amdgcn_fdot2(qh1, uh(A2.z), 0.f, false), false);
        float p3 = __builtin_amdgcn_fdot2(qh0, uh(A3.x), __builtin_amdgcn_fdot2(qh1, uh(A3.z), 0.f, false), false);
        p0 += __shfl_xor(p0, 1);  p1 += __shfl_xor(p1, 1);  p2 += __shfl_xor(p2, 1);  p3 += __shfl_xor(p3, 1);
        p0 += __shfl_xor(p0, 2);  p1 += __shfl_xor(p1, 2);  p2 += __shfl_xor(p2, 2);  p3 += __shfl_xor(p3, 2);
        p0 += __shfl_xor(p0, 4);  p1 += __shfl_xor(p1, 4);  p2 += __shfl_xor(p2, 4);  p3 += __shfl_xor(p3, 4);
        const float l0 = (j + 0 < my_cnt) ? p0 * scale : -INFINITY;
        const float l1 = (j + 1 < my_cnt) ? p1 * scale : -INFINITY;
        const float l2 = (j + 2 < my_cnt) ? p2 * scale : -INFINITY;
        const float l3 = (j + 3 < my_cnt) ? p3 * scale : -INFINITY;
        const float mb = fmaxf(fmaxf(l0, l1), fmaxf(l2, l3));
        const float nm = fmaxf(fmaxf(m, mb), -1e30f);
        const float sc = __expf(m - nm);
        const float w0 = __expf(l0 - nm), w1 = __expf(l1 - nm);
        const float w2 = __expf(l2 - nm), w3 = __expf(l3 - nm);
        den = den * sc + ((w0 + w1) + (w2 + w3));
        half2v v0a = uh(A0.y), v1a = uh(A1.y), v2a = uh(A2.y), v3a = uh(A3.y);
        half2v v0b = uh(A0.w), v1b = uh(A1.w), v2b = uh(A2.w), v3b = uh(A3.w);
        o0 = o0 * sc + w0 * (float)v0a[0] + w1 * (float)v1a[0] + w2 * (float)v2a[0] + w3 * (float)v3a[0];
        o1 = o1 * sc + w0 * (float)v0a[1] + w1 * (float)v1a[1] + w2 * (float)v2a[1] + w3 * (float)v3a[1];
        o2 = o2 * sc + w0 * (float)v0b[0] + w1 * (float)v1b[0] + w2 * (float)v2b[0] + w3 * (float)v3b[0];
        o3 = o3 * sc + w0 * (float)v0b[1] + w1 * (float)v1b[1] + w2 * (float)v2b[1] + w3 * (float)v3b[1];
        m = nm;
        A0 = B0; A1 = B1; A2 = B2; A3 = B3;
        P0 = NP0; P1 = NP1; P2 = NP2; P3 = NP3;
    }

    // merge the two halves (shfl_xor 32)
    {
        const float mo = __shfl_xor(m, 32);
        const float dn = __shfl_xor(den, 32);
        const float b0 = __shfl_xor(o0, 32);
        const float b1 = __shfl_xor(o1, 32);
        const float b2 = __shfl_xor(o2, 32);
        const float b3 = __shfl_xor(o3, 32);
        const float nm = fmaxf(fmaxf(m, mo), -1e30f);
        const float sa = __expf(m - nm);
        const float sb = __expf(mo - nm);
        den = den * sa + dn * sb;
        o0 = o0 * sa + b0 * sb;
        o1 = o1 * sa + b1 * sb;
        o2 = o2 * sa + b2 * sb;
        o3 = o3 * sa + b3 * sb;
    }
    const float inv = 1.f / (den + 1e-16f);
    o0 *= inv; o1 *= inv; o2 *= inv; o3 *= inv;
    o0 += __shfl_xor(o0, 8);  o1 += __shfl_xor(o1, 8);
    o2 += __shfl_xor(o2, 8);  o3 += __shfl_xor(o3, 8);
    o0 += __shfl_xor(o0, 16); o1 += __shfl_xor(o1, 16);
    o2 += __shfl_xor(o2, 16); o3 += __shfl_xor(o3, 16);

    if (lane < 8) {
        float4 sk = *(const float4*)(skip + (long)d * 32 + g * 4);
        float r0 = 0.25f * o0 + sk.x;
        float r1 = 0.25f * o1 + sk.y;
        float r2 = 0.25f * o2 + sk.z;
        float r3 = 0.25f * o3 + sk.w;
        r0 = r0 > 0.f ? r0 : 0.f;
        r1 = r1 > 0.f ? r1 : 0.f;
        r2 = r2 > 0.f ? r2 : 0.f;
        r3 = r3 > 0.f ? r3 : 0.f;
        if (FUSE_CLS) {
            *(float4*)&hrow[wv][g * 4] = make_float4(r0, r1, r2, r3);
        } else {
            *(float4*)(h + (long)d * 32 + g * 4) = make_float4(r0, r1, r2, r3);
        }
    }
    if (FUSE_CLS) {
        __builtin_amdgcn_wave_barrier();
        if (lane < 40) {
            float acc = bc[lane];
#pragma unroll
            for (int l = 0; l < 32; ++l)
                acc = fmaf(hrow[wv][l], wc[l * 40 + lane], acc);
            out[(long)d * 40 + lane] = acc;
        }
    }
}

extern "C" void kernel_launch(void* const* d_in, const int* in_sizes, int n_in,
                              void* d_out, int out_size, void* d_ws, size_t ws_size,
                              hipStream_t stream)
{
    const float* x   = (const float*)d_in[0];
    const int* ei    = (const int*)d_in[1];
    const float* wq1 = (const float*)d_in[2];  const float* bq1 = (const float*)d_in[3];
    const float* wk1 = (const float*)d_in[4];  const float* bk1 = (const float*)d_in[5];
    const float* wv1 = (const float*)d_in[6];  const float* bv1 = (const float*)d_in[7];
    const float* ws1 = (const float*)d_in[8];  const float* bs1 = (const float*)d_in[9];
    const float* wq2 = (const float*)d_in[10]; const float* bq2 = (const float*)d_in[11];
    const float* wk2 = (const float*)d_in[12]; const float* bk2 = (const float*)d_in[13];
    const float* wv2 = (const float*)d_in[14]; const float* bv2 = (const float*)d_in[15];
    const float* ws2 = (const float*)d_in[16]; const float* bs2 = (const float*)d_in[17];
    const float* wc  = (const float*)d_in[18]; const float* bc  = (const float*)d_in[19];

    const int N = in_sizes[0] / 128;   // 50000
    const int E = in_sizes[1] / 2;     // 800000
    const int* src = ei;
    const int* dst = ei + E;

    // workspace layout (bytes, 256-aligned chunks)
    char* p = (char*)d_ws;
    auto take = [&](size_t bytes) { char* r = p; p += (bytes + 255) & ~(size_t)255; return r; };
    unsigned int* qu     = (unsigned int*)take((size_t)N * 64 * 4);    // f16 q, 64 uints/node
    unsigned int* kvp    = (unsigned int*)take((size_t)N * 128 * 4);   // f16 kv, 128 uints/node
    float* skip          = (float*)take((size_t)N * 32 * 4);
    float* h1            = (float*)take((size_t)N * 32 * 4);
    unsigned short* wt1h = (unsigned short*)take(416 * 128 * 2);
    unsigned short* wt1l = (unsigned short*)take(416 * 128 * 2);
    unsigned short* wt2h = (unsigned short*)take(416 * 32 * 2);
    unsigned short* wt2l = (unsigned short*)take(416 * 32 * 2);
    float* bias1         = (float*)take(416 * 4);
    float* bias2         = (float*)take(416 * 4);
    int* deg             = (int*)take((size_t)N * 4);
    int* rowptr          = (int*)take((size_t)(N + 1) * 4);
    int* cursor          = (int*)take((size_t)N * 4);
    int* perm            = (int*)take((size_t)E * 4);
    int* bsum            = (int*)take(64 * 4);
    int* boff            = (int*)take(64 * 4);

    const dim3 projGrid((N + 255) / 256, 4);
    const int eGrid    = (E + 255) / 256;
    const int attnGrid = (N + 3) / 4;          // 4 waves/block
    const int nb       = (N + 1023) / 1024;    // <= 64

    // ---------------- weight prep + CSR build ----------------
    wprep_all<<<832, 128, 0, stream>>>(wq1, bq1, wk1, bk1, wv1, bv1, ws1, bs1,
                                       wq2, bq2, wk2, bk2, wv2, bv2, ws2, bs2,
                                       wt1h, wt1l, bias1, wt2h, wt2l, bias2);
    (void)hipMemsetAsync(deg, 0, (size_t)N * 4, stream);
    hist_kernel<<<eGrid, 256, 0, stream>>>(dst, deg, E);
    scan_part<<<nb, 256, 0, stream>>>(deg, bsum, N);
    scan_tops<<<1, 64, 0, stream>>>(bsum, boff, rowptr, nb, N);
    scan_final<<<nb, 256, 0, stream>>>(deg, boff, rowptr, cursor, N);
    fill_kernel<<<eGrid, 256, 0, stream>>>(src, dst, cursor, perm, E);

    // ---------------- layer 1 ----------------
    proj_mfma<128><<<projGrid, 256, 0, stream>>>(x, wt1h, wt1l, bias1, qu, kvp, skip, N);
    attn_kernel<false><<<attnGrid, 256, 0, stream>>>(qu, kvp, rowptr, perm, skip, h1,
                                                     wc, bc, (float*)d_out, N);

    // ---------------- layer 2 (classifier fused into attn epilogue) --------
    proj_mfma<32><<<projGrid, 256, 0, stream>>>(h1, wt2h, wt2l, bias2, qu, kvp, skip, N);
    attn_kernel<true><<<attnGrid, 256, 0, stream>>>(qu, kvp, rowptr, perm, skip, h1,
                                                    wc, bc, (float*)d_out, N);
}